// Round 15
// baseline (181.642 us; speedup 1.0000x reference)
//
#include <hip/hip_runtime.h>

namespace {

constexpr int NS = 256;      // samples
constexpr int MP = 128;      // patches
constexpr int TSTEPS = 200;  // timesteps
constexpr int BLK = 512;     // 8 waves -> 2 waves/SIMD

typedef _Float16 half8 __attribute__((ext_vector_type(8)));
typedef float f32x4 __attribute__((ext_vector_type(4)));

__device__ __forceinline__ float4 ldg4(const float* p) {
  return *reinterpret_cast<const float4*>(p);
}
__device__ __forceinline__ float clamp01(float v) {
  return fminf(fmaxf(v, 0.0f), 1.0f);
}
// f32 += dot(f16x2, f16x2)
__device__ __forceinline__ float dot2(unsigned a, unsigned b, float c) {
  float d;
  asm("v_dot2_f32_f16 %0, %1, %2, %3" : "=v"(d) : "v"(a), "v"(b), "v"(c));
  return d;
}
// pack two f32 -> f16x2 (RTZ)
__device__ __forceinline__ unsigned pkrtz(float a, float b) {
  typedef __fp16 h2v __attribute__((ext_vector_type(2)));
  h2v r = __builtin_amdgcn_cvt_pkrtz(a, b);
  return __builtin_bit_cast(unsigned, r);
}
__device__ __forceinline__ unsigned bperm(int addr, unsigned src) {
  return (unsigned)__builtin_amdgcn_ds_bpermute(addr, (int)src);
}
// Swizzled uint4 (8 f16) index into f16 Q: 16 quads/row, XOR row-octet
__device__ __forceinline__ int qidx16(int row, int ch) {
  return (row << 4) + (ch ^ ((row >> 3) & 7));
}
__device__ __forceinline__ half8 h8(uint4 v) {
  return __builtin_bit_cast(half8, v);
}

__global__ __launch_bounds__(BLK, 2)
void sir_meta_kernel(const float* __restrict__ Rg,
                     const float* __restrict__ Tg,
                     const float* __restrict__ rho0g,
                     const float* __restrict__ betag,
                     float* __restrict__ outg)
{
  __shared__ __align__(16) float rs[MP];          // 1/rowsum (f32 exact)
  __shared__ __align__(16) float sbin[MP];        // sqrt(beta/neff) (f32 exact)
  __shared__ __align__(16) float scr[BLK];
  __shared__ __align__(16) unsigned xh[64];       // initial x f16 pairs (once)
  __shared__ __align__(16) uint4 q16[MP * 16];    // Q in f16 pairs (32KB)
  __shared__ __align__(16) uint4 gh[MP * 16];     // G in f16 pairs (8KB)

  const int tid = threadIdx.x;
  const int n = blockIdx.x;
  const float* __restrict__ Rn = Rg + (size_t)n * MP * MP;

  // ---- S1: row sums -> rs = 1/rowsum ----
  {
    const int wave = tid >> 6;
    const int lane = tid & 63;
    const int half = lane >> 5;
    const int l32 = lane & 31;
    for (int it = 0; it < 8; ++it) {
      const int row = wave * 16 + it * 2 + half;
      float4 v = ldg4(Rn + row * MP + l32 * 4);
      float s = (v.x + v.y) + (v.z + v.w);
      s += __shfl_xor(s, 1);
      s += __shfl_xor(s, 2);
      s += __shfl_xor(s, 4);
      s += __shfl_xor(s, 8);
      s += __shfl_xor(s, 16);
      if (l32 == 0) rs[row] = 1.0f / s;
    }
  }
  __syncthreads();

  // ---- S2: neff[c] = sum_i Rraw[i][c]*rs[i] -> sbin = sqrt(beta/neff) ----
  {
    const int c = tid & 127;
    const int h = tid >> 7;
    float a = 0.0f;
    #pragma unroll 8
    for (int i = 0; i < 32; ++i) {
      const int ig = h * 32 + i;
      a = fmaf(Rn[ig * MP + c], rs[ig], a);
    }
    scr[tid] = a;
  }
  __syncthreads();
  if (tid < 128)
    sbin[tid] = sqrtf(betag[n] /
        (((scr[tid] + scr[tid + 128]) + (scr[tid + 256] + scr[tid + 384]))));
  __syncthreads();

  // ---- S3a: stage Q = Rraw * diag(sbin) as f16 pairs (swizzled) ----
  {
    #pragma unroll
    for (int u = 0; u < 4; ++u) {
      const int fi8 = u * BLK + tid;
      const int r = fi8 >> 4, c8 = fi8 & 15;
      float4 lo = ldg4(Rn + r * MP + c8 * 8);
      float4 hi = ldg4(Rn + r * MP + c8 * 8 + 4);
      float4 s0 = *reinterpret_cast<const float4*>(&sbin[c8 * 8]);
      float4 s1 = *reinterpret_cast<const float4*>(&sbin[c8 * 8 + 4]);
      uint4 w;
      w.x = pkrtz(lo.x * s0.x, lo.y * s0.y);
      w.y = pkrtz(lo.z * s0.z, lo.w * s0.w);
      w.z = pkrtz(hi.x * s1.x, hi.y * s1.y);
      w.w = pkrtz(hi.z * s1.z, hi.w * s1.w);
      q16[qidx16(r, c8)] = w;
    }
  }
  __syncthreads();

  // ---- S3b: 8-wave f16 dot2 GEMM -> gh (G = diag(rs) Q Q^T diag(rs)) ----
  {
    const int wv = tid >> 6;
    const int g4 = (tid >> 4) & 3;
    const int k4 = tid & 15;
    const int rb = wv * 16 + g4 * 4;
    const int cb = k4 * 8;
    float acc[4][8];
    #pragma unroll
    for (int r = 0; r < 4; ++r)
      #pragma unroll
      for (int c = 0; c < 8; ++c) acc[r][c] = 0.0f;
    #pragma unroll 4
    for (int ch = 0; ch < 16; ++ch) {
      uint4 qa[4], qb[8];
      #pragma unroll
      for (int r = 0; r < 4; ++r) qa[r] = q16[qidx16(rb + r, ch)];
      #pragma unroll
      for (int c = 0; c < 8; ++c) qb[c] = q16[qidx16(cb + c, ch)];
      #pragma unroll
      for (int r = 0; r < 4; ++r) {
        #pragma unroll
        for (int c = 0; c < 8; ++c) {
          float a = acc[r][c];
          a = dot2(qa[r].x, qb[c].x, a);
          a = dot2(qa[r].y, qb[c].y, a);
          a = dot2(qa[r].z, qb[c].z, a);
          a = dot2(qa[r].w, qb[c].w, a);
          acc[r][c] = a;
        }
      }
    }
    float rsc[8];
    #pragma unroll
    for (int c = 0; c < 8; ++c) rsc[c] = rs[cb + c];
    #pragma unroll
    for (int r = 0; r < 4; ++r) {
      const float rr = rs[rb + r];
      uint4 w;
      w.x = pkrtz(acc[r][0] * rr * rsc[0], acc[r][1] * rr * rsc[1]);
      w.y = pkrtz(acc[r][2] * rr * rsc[2], acc[r][3] * rr * rsc[3]);
      w.z = pkrtz(acc[r][4] * rr * rsc[4], acc[r][5] * rr * rsc[5]);
      w.w = pkrtz(acc[r][6] * rr * rsc[6], acc[r][7] * rr * rsc[7]);
      gh[(rb + r) * 16 + k4] = w;
    }
  }
  // initial x as f16 pairs
  if (tid < 64) {
    const float* xp = rho0g + ((size_t)n * MP + 2 * tid) * 3;
    xh[tid] = pkrtz(xp[0], xp[3]);
  }
  __syncthreads();

  // ---- loop: every wave redundantly computes full y = G x via 32 MFMA ----
  // Lane (col, kg): col = l&15, kg = l>>4.
  // A-frag tile I: af[I][c] = gh[(16I+col)*16 + 4c+kg]  (R14-verified layout)
  // D tile I: lane reg r holds y[16I + 4kg + r]  (any col; cols identical)
  // Lane owns state rows rowA = 16(col>>1) + 4kg + 2(col&1), rowB = rowA+1.
  const int w = tid >> 6;
  const int l = tid & 63;
  const int col = l & 15;
  const int kg = l >> 4;
  const bool t1 = (col & 1) != 0;
  const bool i0 = (col & 2) != 0;   // I* bit 0
  const bool i1 = (col & 4) != 0;   // I* bit 1
  const bool i2 = (col & 8) != 0;   // I* bit 2
  const int Istar = col >> 1;
  const int rowA = 16 * Istar + 4 * kg + 2 * (col & 1);

  uint4 af[8][4];
  #pragma unroll
  for (int I = 0; I < 8; ++I)
    #pragma unroll
    for (int c = 0; c < 4; ++c)
      af[I][c] = gh[(16 * I + col) * 16 + 4 * c + kg];

  // bpermute byte-addresses: id m = 16c+4kg+j lives in lane 2(m>>3)+(m&1)+16((m>>1)&3)
  int baddr[4][4];
  #pragma unroll
  for (int c = 0; c < 4; ++c)
    #pragma unroll
    for (int j = 0; j < 4; ++j) {
      const int m = 16 * c + 4 * kg + j;
      baddr[c][j] = 4 * (2 * (m >> 3) + (m & 1) + 16 * ((m >> 1) & 3));
    }

  // initial B-fragments from LDS (broadcast reads, once)
  const uint4* xq4 = reinterpret_cast<const uint4*>(xh);
  uint4 bf0 = xq4[kg];
  uint4 bf1 = xq4[4 + kg];
  uint4 bf2 = xq4[8 + kg];
  uint4 bf3 = xq4[12 + kg];

  const float* Tn = Tg + n * 9;
  const float T00 = Tn[0], T01 = Tn[1], T02 = Tn[2];
  const float T10 = Tn[3], T11 = Tn[4], T12 = Tn[5];
  const float T20 = Tn[6], T21 = Tn[7], T22 = Tn[8];

  const float* rp = rho0g + ((size_t)n * MP + rowA) * 3;
  float a0 = rp[0], a1 = rp[1], a2 = rp[2];   // row rowA
  float b0 = rp[3], b1 = rp[4], b2 = rp[5];   // row rowA+1

  const bool storer = (Istar == w);           // wave w stores rows [16w,16w+16)
  float4* outp = reinterpret_cast<float4*>(outg) + (size_t)n * TSTEPS * MP + rowA;

  for (int s = 0; s < TSTEPS; ++s) {
    // 8 independent 4-deep MFMA chains (full y, redundant per wave)
    f32x4 acc[8];
    #pragma unroll
    for (int I = 0; I < 8; ++I) {
      f32x4 a = {0.f, 0.f, 0.f, 0.f};
      a = __builtin_amdgcn_mfma_f32_16x16x32_f16(h8(af[I][0]), h8(bf0), a, 0, 0, 0);
      a = __builtin_amdgcn_mfma_f32_16x16x32_f16(h8(af[I][1]), h8(bf1), a, 0, 0, 0);
      a = __builtin_amdgcn_mfma_f32_16x16x32_f16(h8(af[I][2]), h8(bf2), a, 0, 0, 0);
      a = __builtin_amdgcn_mfma_f32_16x16x32_f16(h8(af[I][3]), h8(bf3), a, 0, 0, 0);
      acc[I] = a;
    }

    // off-chain: emit pre-update state (wave w -> its 16 rows)
    const float SA = 1.0f - ((a0 + a1) + a2);
    const float SB = 1.0f - ((b0 + b1) + b2);
    if (storer) {
      outp[0] = make_float4(SA, a0, a1, a2);
      outp[1] = make_float4(SB, b0, b1, b2);
    }
    outp += MP;

    // static select of yA = acc[I*][2t*], yB = acc[I*][2t*+1]
    float qA[8], qB[8];
    #pragma unroll
    for (int I = 0; I < 8; ++I) {
      qA[I] = t1 ? acc[I][2] : acc[I][0];
      qB[I] = t1 ? acc[I][3] : acc[I][1];
    }
    const float uA0 = i0 ? qA[1] : qA[0];
    const float uA1 = i0 ? qA[3] : qA[2];
    const float uA2 = i0 ? qA[5] : qA[4];
    const float uA3 = i0 ? qA[7] : qA[6];
    const float vA0 = i1 ? uA1 : uA0;
    const float vA1 = i1 ? uA3 : uA2;
    const float yA = i2 ? vA1 : vA0;
    const float uB0 = i0 ? qB[1] : qB[0];
    const float uB1 = i0 ? qB[3] : qB[2];
    const float uB2 = i0 ? qB[5] : qB[4];
    const float uB3 = i0 ? qB[7] : qB[6];
    const float vB0 = i1 ? uB1 : uB0;
    const float vB1 = i1 ? uB3 : uB2;
    const float yB = i2 ? vB1 : vB0;

    // state update (n0 first -> feeds redistribution)
    const float n0A = clamp01(fmaf(a0, T00, fmaf(a1, T10, fmaf(a2, T20, SA * yA))));
    const float n0B = clamp01(fmaf(b0, T00, fmaf(b1, T10, fmaf(b2, T20, SB * yB))));
    const unsigned xnew = pkrtz(n0A, n0B);

    // in-wave crossbar: rebuild B-fragments for next step (no LDS, no barrier)
    bf0 = make_uint4(bperm(baddr[0][0], xnew), bperm(baddr[0][1], xnew),
                     bperm(baddr[0][2], xnew), bperm(baddr[0][3], xnew));
    bf1 = make_uint4(bperm(baddr[1][0], xnew), bperm(baddr[1][1], xnew),
                     bperm(baddr[1][2], xnew), bperm(baddr[1][3], xnew));
    bf2 = make_uint4(bperm(baddr[2][0], xnew), bperm(baddr[2][1], xnew),
                     bperm(baddr[2][2], xnew), bperm(baddr[2][3], xnew));
    bf3 = make_uint4(bperm(baddr[3][0], xnew), bperm(baddr[3][1], xnew),
                     bperm(baddr[3][2], xnew), bperm(baddr[3][3], xnew));

    // off-chain: rest of state
    const float n1A = clamp01(fmaf(a0, T01, fmaf(a1, T11, a2 * T21)));
    const float n2A = clamp01(fmaf(a0, T02, fmaf(a1, T12, a2 * T22)));
    const float n1B = clamp01(fmaf(b0, T01, fmaf(b1, T11, b2 * T21)));
    const float n2B = clamp01(fmaf(b0, T02, fmaf(b1, T12, b2 * T22)));
    a0 = n0A; a1 = n1A; a2 = n2A;
    b0 = n0B; b1 = n1B; b2 = n2B;
  }
}

} // namespace

extern "C" void kernel_launch(void* const* d_in, const int* in_sizes, int n_in,
                              void* d_out, int out_size, void* d_ws, size_t ws_size,
                              hipStream_t stream)
{
  const float* Rg    = (const float*)d_in[0];
  const float* Tg    = (const float*)d_in[1];
  const float* rho0g = (const float*)d_in[2];
  const float* betag = (const float*)d_in[3];
  float* outg = (float*)d_out;
  sir_meta_kernel<<<NS, BLK, 0, stream>>>(Rg, Tg, rho0g, betag, outg);
}

// Round 16
// 120.727 us; speedup vs baseline: 1.5046x; 1.5046x over previous
//
#include <hip/hip_runtime.h>

namespace {

constexpr int NS = 256;      // samples
constexpr int MP = 128;      // patches
constexpr int TSTEPS = 200;  // timesteps
constexpr int BLK = 512;     // 8 waves for setup; waves 0-3 run the loop

typedef _Float16 half8 __attribute__((ext_vector_type(8)));
typedef float f32x4 __attribute__((ext_vector_type(4)));

__device__ __forceinline__ float4 ldg4(const float* p) {
  return *reinterpret_cast<const float4*>(p);
}
__device__ __forceinline__ float clamp01(float v) {
  return fminf(fmaxf(v, 0.0f), 1.0f);
}
// f32 += dot(f16x2, f16x2)
__device__ __forceinline__ float dot2(unsigned a, unsigned b, float c) {
  float d;
  asm("v_dot2_f32_f16 %0, %1, %2, %3" : "=v"(d) : "v"(a), "v"(b), "v"(c));
  return d;
}
// pack two f32 -> f16x2 (RTZ)
__device__ __forceinline__ unsigned pkrtz(float a, float b) {
  typedef __fp16 h2v __attribute__((ext_vector_type(2)));
  h2v r = __builtin_amdgcn_cvt_pkrtz(a, b);
  return __builtin_bit_cast(unsigned, r);
}
// Swizzled uint4 (8 f16) index into f16 Q: 16 quads/row, XOR row-octet
__device__ __forceinline__ int qidx16(int row, int ch) {
  return (row << 4) + (ch ^ ((row >> 3) & 7));
}
__device__ __forceinline__ half8 h8(uint4 v) {
  return __builtin_bit_cast(half8, v);
}

__global__ __launch_bounds__(BLK, 2)
void sir_meta_kernel(const float* __restrict__ Rg,
                     const float* __restrict__ Tg,
                     const float* __restrict__ rho0g,
                     const float* __restrict__ betag,
                     float* __restrict__ outg)
{
  __shared__ __align__(16) float rs[MP];          // 1/rowsum (f32 exact)
  __shared__ __align__(16) float sbin[MP];        // sqrt(beta/neff) (f32 exact)
  __shared__ __align__(16) float scr[BLK];
  __shared__ __align__(16) unsigned xw[4][64];    // per-wave private x regions
  __shared__ __align__(16) uint4 q16[MP * 16];    // Q in f16 pairs (32KB)
  __shared__ __align__(16) uint4 gh[MP * 16];     // G in f16 pairs (8KB)

  const int tid = threadIdx.x;
  const int n = blockIdx.x;
  const float* __restrict__ Rn = Rg + (size_t)n * MP * MP;

  // ---- S1: row sums -> rs = 1/rowsum ----
  {
    const int wave = tid >> 6;
    const int lane = tid & 63;
    const int half = lane >> 5;
    const int l32 = lane & 31;
    for (int it = 0; it < 8; ++it) {
      const int row = wave * 16 + it * 2 + half;
      float4 v = ldg4(Rn + row * MP + l32 * 4);
      float s = (v.x + v.y) + (v.z + v.w);
      s += __shfl_xor(s, 1);
      s += __shfl_xor(s, 2);
      s += __shfl_xor(s, 4);
      s += __shfl_xor(s, 8);
      s += __shfl_xor(s, 16);
      if (l32 == 0) rs[row] = 1.0f / s;
    }
  }
  __syncthreads();

  // ---- S2: neff[c] = sum_i Rraw[i][c]*rs[i] -> sbin = sqrt(beta/neff) ----
  {
    const int c = tid & 127;
    const int h = tid >> 7;
    float a = 0.0f;
    #pragma unroll 8
    for (int i = 0; i < 32; ++i) {
      const int ig = h * 32 + i;
      a = fmaf(Rn[ig * MP + c], rs[ig], a);
    }
    scr[tid] = a;
  }
  __syncthreads();
  if (tid < 128)
    sbin[tid] = sqrtf(betag[n] /
        (((scr[tid] + scr[tid + 128]) + (scr[tid + 256] + scr[tid + 384]))));
  __syncthreads();

  // ---- S3a: stage Q = Rraw * diag(sbin) as f16 pairs (swizzled) ----
  {
    #pragma unroll
    for (int u = 0; u < 4; ++u) {
      const int fi8 = u * BLK + tid;
      const int r = fi8 >> 4, c8 = fi8 & 15;
      float4 lo = ldg4(Rn + r * MP + c8 * 8);
      float4 hi = ldg4(Rn + r * MP + c8 * 8 + 4);
      float4 s0 = *reinterpret_cast<const float4*>(&sbin[c8 * 8]);
      float4 s1 = *reinterpret_cast<const float4*>(&sbin[c8 * 8 + 4]);
      uint4 w;
      w.x = pkrtz(lo.x * s0.x, lo.y * s0.y);
      w.y = pkrtz(lo.z * s0.z, lo.w * s0.w);
      w.z = pkrtz(hi.x * s1.x, hi.y * s1.y);
      w.w = pkrtz(hi.z * s1.z, hi.w * s1.w);
      q16[qidx16(r, c8)] = w;
    }
  }
  __syncthreads();

  // ---- S3b: 8-wave f16 dot2 GEMM -> gh (G = diag(rs) Q Q^T diag(rs)) ----
  {
    const int wv = tid >> 6;
    const int g4 = (tid >> 4) & 3;
    const int k4 = tid & 15;
    const int rb = wv * 16 + g4 * 4;
    const int cb = k4 * 8;
    float acc[4][8];
    #pragma unroll
    for (int r = 0; r < 4; ++r)
      #pragma unroll
      for (int c = 0; c < 8; ++c) acc[r][c] = 0.0f;
    #pragma unroll 4
    for (int ch = 0; ch < 16; ++ch) {
      uint4 qa[4], qb[8];
      #pragma unroll
      for (int r = 0; r < 4; ++r) qa[r] = q16[qidx16(rb + r, ch)];
      #pragma unroll
      for (int c = 0; c < 8; ++c) qb[c] = q16[qidx16(cb + c, ch)];
      #pragma unroll
      for (int r = 0; r < 4; ++r) {
        #pragma unroll
        for (int c = 0; c < 8; ++c) {
          float a = acc[r][c];
          a = dot2(qa[r].x, qb[c].x, a);
          a = dot2(qa[r].y, qb[c].y, a);
          a = dot2(qa[r].z, qb[c].z, a);
          a = dot2(qa[r].w, qb[c].w, a);
          acc[r][c] = a;
        }
      }
    }
    float rsc[8];
    #pragma unroll
    for (int c = 0; c < 8; ++c) rsc[c] = rs[cb + c];
    #pragma unroll
    for (int r = 0; r < 4; ++r) {
      const float rr = rs[rb + r];
      uint4 w;
      w.x = pkrtz(acc[r][0] * rr * rsc[0], acc[r][1] * rr * rsc[1]);
      w.y = pkrtz(acc[r][2] * rr * rsc[2], acc[r][3] * rr * rsc[3]);
      w.z = pkrtz(acc[r][4] * rr * rsc[4], acc[r][5] * rr * rsc[5]);
      w.w = pkrtz(acc[r][6] * rr * rsc[6], acc[r][7] * rr * rsc[7]);
      gh[(rb + r) * 16 + k4] = w;
    }
  }
  // initial x into all 4 per-wave regions (slot m2 = pair {2m2, 2m2+1})
  if (tid < 256) {
    const int m2 = tid & 63;
    const float* xp = rho0g + ((size_t)n * MP + 2 * m2) * 3;
    xw[tid >> 6][m2] = pkrtz(xp[0], xp[3]);
  }
  __syncthreads();

  // ---- waves 4-7 retire; waves 0-3 run barrier-free self-sufficient loops ----
  if (tid >= 256) return;
  const int w = tid >> 6;
  const int l = tid & 63;
  const int col = l & 15;
  const int kg = l >> 4;
  const bool t1 = (col & 1) != 0;
  const bool i0 = (col & 2) != 0;
  const bool i1 = (col & 4) != 0;
  const bool i2 = (col & 8) != 0;
  const int Istar = col >> 1;
  const int rowA = 16 * Istar + 4 * kg + 2 * (col & 1);   // even; rowB = rowA+1

  // full G as A-fragments: 32 uint4 = 128 VGPRs (R14/R15-verified layout)
  uint4 af[8][4];
  #pragma unroll
  for (int I = 0; I < 8; ++I)
    #pragma unroll
    for (int c = 0; c < 4; ++c)
      af[I][c] = gh[(16 * I + col) * 16 + 4 * c + kg];

  const float* Tn = Tg + n * 9;
  const float T00 = Tn[0], T01 = Tn[1], T02 = Tn[2];
  const float T10 = Tn[3], T11 = Tn[4], T12 = Tn[5];
  const float T20 = Tn[6], T21 = Tn[7], T22 = Tn[8];

  const float* rp = rho0g + ((size_t)n * MP + rowA) * 3;
  float a0 = rp[0], a1 = rp[1], a2 = rp[2];   // row rowA
  float b0 = rp[3], b1 = rp[4], b2 = rp[5];   // row rowA+1

  const bool storer = ((col >> 2) == w);      // wave w stores rows [32w,32w+32)
  const int xslot = rowA >> 1;                // this lane's x pair slot
  const uint4* xq4 = reinterpret_cast<const uint4*>(&xw[w][0]);
  unsigned* xwr = &xw[w][0];
  float4* outp = reinterpret_cast<float4*>(outg) + (size_t)n * TSTEPS * MP + rowA;

  for (int s = 0; s < TSTEPS; ++s) {
    // chain head: 4 broadcast b128 reads from this wave's private region
    const uint4 bf0 = xq4[kg];
    const uint4 bf1 = xq4[4 + kg];
    const uint4 bf2 = xq4[8 + kg];
    const uint4 bf3 = xq4[12 + kg];

    // off-chain: emit pre-update state
    const float SA = 1.0f - ((a0 + a1) + a2);
    const float SB = 1.0f - ((b0 + b1) + b2);
    if (storer) {
      outp[0] = make_float4(SA, a0, a1, a2);
      outp[1] = make_float4(SB, b0, b1, b2);
    }
    outp += MP;

    // 8 independent 4-deep MFMA chains: full y = G x in this wave
    f32x4 acc[8];
    #pragma unroll
    for (int I = 0; I < 8; ++I) {
      f32x4 a = {0.f, 0.f, 0.f, 0.f};
      a = __builtin_amdgcn_mfma_f32_16x16x32_f16(h8(af[I][0]), h8(bf0), a, 0, 0, 0);
      a = __builtin_amdgcn_mfma_f32_16x16x32_f16(h8(af[I][1]), h8(bf1), a, 0, 0, 0);
      a = __builtin_amdgcn_mfma_f32_16x16x32_f16(h8(af[I][2]), h8(bf2), a, 0, 0, 0);
      a = __builtin_amdgcn_mfma_f32_16x16x32_f16(h8(af[I][3]), h8(bf3), a, 0, 0, 0);
      acc[I] = a;
    }

    // static select (R15-verified): yA = acc[I*][2t*], yB = acc[I*][2t*+1]
    float qA[8], qB[8];
    #pragma unroll
    for (int I = 0; I < 8; ++I) {
      qA[I] = t1 ? acc[I][2] : acc[I][0];
      qB[I] = t1 ? acc[I][3] : acc[I][1];
    }
    const float uA0 = i0 ? qA[1] : qA[0];
    const float uA1 = i0 ? qA[3] : qA[2];
    const float uA2 = i0 ? qA[5] : qA[4];
    const float uA3 = i0 ? qA[7] : qA[6];
    const float vA0 = i1 ? uA1 : uA0;
    const float vA1 = i1 ? uA3 : uA2;
    const float yA = i2 ? vA1 : vA0;
    const float uB0 = i0 ? qB[1] : qB[0];
    const float uB1 = i0 ? qB[3] : qB[2];
    const float uB2 = i0 ? qB[5] : qB[4];
    const float uB3 = i0 ? qB[7] : qB[6];
    const float vB0 = i1 ? uB1 : uB0;
    const float vB1 = i1 ? uB3 : uB2;
    const float yB = i2 ? vB1 : vB0;

    // chain tail: n0 both rows -> one u32 write into private region
    const float n0A = clamp01(fmaf(a0, T00, fmaf(a1, T10, fmaf(a2, T20, SA * yA))));
    const float n0B = clamp01(fmaf(b0, T00, fmaf(b1, T10, fmaf(b2, T20, SB * yB))));
    xwr[xslot] = pkrtz(n0A, n0B);

    // off-chain under the write: rest of state update
    const float n1A = clamp01(fmaf(a0, T01, fmaf(a1, T11, a2 * T21)));
    const float n2A = clamp01(fmaf(a0, T02, fmaf(a1, T12, a2 * T22)));
    const float n1B = clamp01(fmaf(b0, T01, fmaf(b1, T11, b2 * T21)));
    const float n2B = clamp01(fmaf(b0, T02, fmaf(b1, T12, b2 * T22)));
    a0 = n0A; a1 = n1A; a2 = n2A;
    b0 = n0B; b1 = n1B; b2 = n2B;

    // wave-local ordering only: write visible before next iter's reads
    asm volatile("s_waitcnt lgkmcnt(0)" ::: "memory");
  }
}

} // namespace

extern "C" void kernel_launch(void* const* d_in, const int* in_sizes, int n_in,
                              void* d_out, int out_size, void* d_ws, size_t ws_size,
                              hipStream_t stream)
{
  const float* Rg    = (const float*)d_in[0];
  const float* Tg    = (const float*)d_in[1];
  const float* rho0g = (const float*)d_in[2];
  const float* betag = (const float*)d_in[3];
  float* outg = (float*)d_out;
  sir_meta_kernel<<<NS, BLK, 0, stream>>>(Rg, Tg, rho0g, betag, outg);
}

// Round 17
// 70.376 us; speedup vs baseline: 2.5810x; 1.7155x over previous
//
#include <hip/hip_runtime.h>

namespace {

constexpr int NS = 256;      // samples
constexpr int MP = 128;      // patches
constexpr int TSTEPS = 200;  // timesteps
constexpr int BLK = 512;     // 8 waves -> 2 waves/SIMD (proven optimum)

typedef _Float16 half8 __attribute__((ext_vector_type(8)));
typedef __fp16 h8v __attribute__((ext_vector_type(8)));
typedef float f32x4 __attribute__((ext_vector_type(4)));

__device__ __forceinline__ float4 ldg4(const float* p) {
  return *reinterpret_cast<const float4*>(p);
}
__device__ __forceinline__ float clamp01(float v) {
  return fminf(fmaxf(v, 0.0f), 1.0f);
}
// LDS-visibility barrier that does NOT drain vmcnt (stores stay in flight).
__device__ __forceinline__ void step_barrier() {
  asm volatile("s_waitcnt lgkmcnt(0)" ::: "memory");
  __builtin_amdgcn_s_barrier();
  asm volatile("" ::: "memory");
}
// pack two f32 -> f16x2 (RTZ)
__device__ __forceinline__ unsigned pkrtz(float a, float b) {
  typedef __fp16 h2v __attribute__((ext_vector_type(2)));
  h2v r = __builtin_amdgcn_cvt_pkrtz(a, b);
  return __builtin_bit_cast(unsigned, r);
}
// elementwise f16x8 multiply (4x v_pk_mul_f16)
__device__ __forceinline__ uint4 pkmul4(uint4 a, uint4 b) {
  h8v x = __builtin_bit_cast(h8v, a);
  h8v y = __builtin_bit_cast(h8v, b);
  h8v z = x * y;
  return __builtin_bit_cast(uint4, z);
}
// fetch value from lane^1 (quad_perm [1,0,3,2])
__device__ __forceinline__ float dpp_xor1(float x) {
  int yi = __builtin_amdgcn_update_dpp(0, __float_as_int(x), 0xB1, 0xF, 0xF, true);
  return __int_as_float(yi);
}
// Swizzled uint4 (8 f16) index into f16 Q: 16 quads/row, XOR row-octet
__device__ __forceinline__ int qidx16(int row, int ch) {
  return (row << 4) + (ch ^ ((row >> 3) & 7));
}
__device__ __forceinline__ half8 h8(uint4 v) {
  return __builtin_bit_cast(half8, v);
}

__global__ __launch_bounds__(BLK, 2)
void sir_meta_kernel(const float* __restrict__ Rg,
                     const float* __restrict__ Tg,
                     const float* __restrict__ rho0g,
                     const float* __restrict__ betag,
                     float* __restrict__ outg)
{
  __shared__ __align__(16) float rs[MP];          // 1/rowsum (f32 exact)
  __shared__ __align__(16) float bnv[MP];         // beta/neff (f32)
  __shared__ __align__(16) unsigned binv16[64];   // beta/neff as f16 pairs
  __shared__ __align__(16) float scr[BLK];
  __shared__ __align__(16) unsigned xh[2][64];    // x as f16 pairs, dbuffered
  __shared__ __align__(16) uint4 q16[MP * 16];    // RAW R in f16 pairs (32KB)
  __shared__ __align__(16) uint4 gh[MP * 16];     // G in f16 pairs (8KB)

  const int tid = threadIdx.x;
  const int n = blockIdx.x;
  const float* __restrict__ Rn = Rg + (size_t)n * MP * MP;

  // ---- S1: row sums -> rs = 1/rowsum ----
  {
    const int wave = tid >> 6;
    const int lane = tid & 63;
    const int half = lane >> 5;
    const int l32 = lane & 31;
    for (int it = 0; it < 8; ++it) {
      const int row = wave * 16 + it * 2 + half;
      float4 v = ldg4(Rn + row * MP + l32 * 4);
      float s = (v.x + v.y) + (v.z + v.w);
      s += __shfl_xor(s, 1);
      s += __shfl_xor(s, 2);
      s += __shfl_xor(s, 4);
      s += __shfl_xor(s, 8);
      s += __shfl_xor(s, 16);
      if (l32 == 0) rs[row] = 1.0f / s;
    }
  }
  __syncthreads();

  // ---- S2: neff[c] = sum_i Rraw[i][c]*rs[i] -> bnv = beta/neff ----
  {
    const int c = tid & 127;
    const int h = tid >> 7;
    float a = 0.0f;
    #pragma unroll 8
    for (int i = 0; i < 32; ++i) {
      const int ig = h * 32 + i;
      a = fmaf(Rn[ig * MP + c], rs[ig], a);
    }
    scr[tid] = a;
  }
  __syncthreads();
  if (tid < 128)
    bnv[tid] = betag[n] /
        (((scr[tid] + scr[tid + 128]) + (scr[tid + 256] + scr[tid + 384])));
  __syncthreads();

  // ---- S3a: stage RAW R as f16 pairs (swizzled); pack binv16 ----
  {
    #pragma unroll
    for (int u = 0; u < 4; ++u) {
      const int fi8 = u * BLK + tid;
      const int r = fi8 >> 4, c8 = fi8 & 15;
      float4 lo = ldg4(Rn + r * MP + c8 * 8);
      float4 hi = ldg4(Rn + r * MP + c8 * 8 + 4);
      uint4 w;
      w.x = pkrtz(lo.x, lo.y);
      w.y = pkrtz(lo.z, lo.w);
      w.z = pkrtz(hi.x, hi.y);
      w.w = pkrtz(hi.z, hi.w);
      q16[qidx16(r, c8)] = w;
    }
    if (tid < 64) binv16[tid] = pkrtz(bnv[2 * tid], bnv[2 * tid + 1]);
  }
  __syncthreads();

  // ---- S3b: MFMA GEMM. Wave J computes G tiles (I=0..7, J). ----
  // A = raw R tile-I rows (R14-verified frag gather); B = binv-scaled tile-J.
  // D (m89): lane(col,kg) reg r = G[16I+4kg+r][16J+col] (pre-scale).
  {
    const int J = tid >> 6;
    const int l = tid & 63;
    const int col = l & 15;
    const int kg = l >> 4;
    const uint4* bnv4 = reinterpret_cast<const uint4*>(binv16);
    uint4 bfj[4];
    #pragma unroll
    for (int c = 0; c < 4; ++c)
      bfj[c] = pkmul4(q16[qidx16(16 * J + col, 4 * c + kg)], bnv4[4 * c + kg]);
    const float rscol = rs[16 * J + col];
    unsigned* ghu = reinterpret_cast<unsigned*>(gh);
    #pragma unroll
    for (int I = 0; I < 8; ++I) {
      const uint4 af0 = q16[qidx16(16 * I + col, 0 + kg)];
      const uint4 af1 = q16[qidx16(16 * I + col, 4 + kg)];
      const uint4 af2 = q16[qidx16(16 * I + col, 8 + kg)];
      const uint4 af3 = q16[qidx16(16 * I + col, 12 + kg)];
      f32x4 a = {0.f, 0.f, 0.f, 0.f};
      a = __builtin_amdgcn_mfma_f32_16x16x32_f16(h8(af0), h8(bfj[0]), a, 0, 0, 0);
      a = __builtin_amdgcn_mfma_f32_16x16x32_f16(h8(af1), h8(bfj[1]), a, 0, 0, 0);
      a = __builtin_amdgcn_mfma_f32_16x16x32_f16(h8(af2), h8(bfj[2]), a, 0, 0, 0);
      a = __builtin_amdgcn_mfma_f32_16x16x32_f16(h8(af3), h8(bfj[3]), a, 0, 0, 0);
      #pragma unroll
      for (int r = 0; r < 4; ++r) {
        const int ROW = 16 * I + 4 * kg + r;
        const float val = a[r] * rs[ROW] * rscol;
        const float nb = dpp_xor1(val);            // neighbor col's scaled val
        if ((col & 1) == 0)
          ghu[ROW * 64 + 8 * J + (col >> 1)] = pkrtz(val, nb);
      }
    }
  }
  // initial x as f16 pairs
  if (tid < 64) {
    const float* xp = rho0g + ((size_t)n * MP + 2 * tid) * 3;
    xh[0][tid] = pkrtz(xp[0], xp[3]);
  }
  __syncthreads();

  // ---- R14 loop (verbatim): wave w owns G rows [16w..16w+16) ----
  const int w = tid >> 6;
  const int l = tid & 63;
  const int col = l & 15;
  const int kg = l >> 4;
  const int jrow = 16 * w + 4 * kg + col;   // this lane's state row (col<4)
  const bool writer = (col < 4);

  uint4 af0 = gh[(16 * w + col) * 16 + 0 + kg];
  uint4 af1 = gh[(16 * w + col) * 16 + 4 + kg];
  uint4 af2 = gh[(16 * w + col) * 16 + 8 + kg];
  uint4 af3 = gh[(16 * w + col) * 16 + 12 + kg];

  const float* Tn = Tg + n * 9;
  const float T00 = Tn[0], T01 = Tn[1], T02 = Tn[2];
  const float T10 = Tn[3], T11 = Tn[4], T12 = Tn[5];
  const float T20 = Tn[6], T21 = Tn[7], T22 = Tn[8];

  float r0 = 0.f, r1 = 0.f, r2 = 0.f;
  if (writer) {
    const float* rp = rho0g + ((size_t)n * MP + jrow) * 3;
    r0 = rp[0]; r1 = rp[1]; r2 = rp[2];
  }

  float4* outp = reinterpret_cast<float4*>(outg) + (size_t)n * TSTEPS * MP + jrow;
  const bool xwriter = writer && ((col & 1) == 0);
  const int xslot = jrow >> 1;              // valid when col even

  for (int s = 0; s < TSTEPS; ++s) {
    // chain head: 4 broadcast uint4 x-reads (4 distinct addrs/wave)
    const uint4* xq4 = reinterpret_cast<const uint4*>(&xh[s & 1][0]);
    const uint4 b0 = xq4[kg];
    const uint4 b1 = xq4[4 + kg];
    const uint4 b2 = xq4[8 + kg];
    const uint4 b3 = xq4[12 + kg];

    // off-chain: emit pre-update state (coalesced 16-lane store per wave)
    const float S = 1.0f - ((r0 + r1) + r2);
    if (writer) *outp = make_float4(S, r0, r1, r2);
    outp += MP;

    // two 2-deep MFMA chains (K = 128 in 32-chunks), summed at select
    f32x4 accA = {0.f, 0.f, 0.f, 0.f};
    f32x4 accB = {0.f, 0.f, 0.f, 0.f};
    accA = __builtin_amdgcn_mfma_f32_16x16x32_f16(h8(af0), h8(b0), accA, 0, 0, 0);
    accB = __builtin_amdgcn_mfma_f32_16x16x32_f16(h8(af1), h8(b1), accB, 0, 0, 0);
    accA = __builtin_amdgcn_mfma_f32_16x16x32_f16(h8(af2), h8(b2), accA, 0, 0, 0);
    accB = __builtin_amdgcn_mfma_f32_16x16x32_f16(h8(af3), h8(b3), accB, 0, 0, 0);

    // static select of this lane's row-sum (reg index = col, cndmask tree)
    const float tA0 = (col & 1) ? accA[1] : accA[0];
    const float tA1 = (col & 1) ? accA[3] : accA[2];
    const float tB0 = (col & 1) ? accB[1] : accB[0];
    const float tB1 = (col & 1) ? accB[3] : accB[2];
    const float y = ((col & 2) ? tA1 : tA0) + ((col & 2) ? tB1 : tB0);

    // state update + clip
    const float ni = S * y;
    const float n0 = clamp01(fmaf(r0, T00, fmaf(r1, T10, fmaf(r2, T20, ni))));
    const float n1 = clamp01(fmaf(r0, T01, fmaf(r1, T11, r2 * T21)));
    const float n2 = clamp01(fmaf(r0, T02, fmaf(r1, T12, r2 * T22)));

    // pack adjacent rows' n0 (col pairs 0-1, 2-3 via quad_perm xor1)
    const float nb = dpp_xor1(n0);
    if (xwriter) xh[(s & 1) ^ 1][xslot] = pkrtz(n0, nb);

    r0 = n0; r1 = n1; r2 = n2;

    // LDS-only barrier: x write visible; global stores stay in flight
    step_barrier();
  }
}

} // namespace

extern "C" void kernel_launch(void* const* d_in, const int* in_sizes, int n_in,
                              void* d_out, int out_size, void* d_ws, size_t ws_size,
                              hipStream_t stream)
{
  const float* Rg    = (const float*)d_in[0];
  const float* Tg    = (const float*)d_in[1];
  const float* rho0g = (const float*)d_in[2];
  const float* betag = (const float*)d_in[3];
  float* outg = (float*)d_out;
  sir_meta_kernel<<<NS, BLK, 0, stream>>>(Rg, Tg, rho0g, betag, outg);
}

// Round 18
// 68.155 us; speedup vs baseline: 2.6651x; 1.0326x over previous
//
#include <hip/hip_runtime.h>

namespace {

constexpr int NS = 256;      // samples
constexpr int MP = 128;      // patches
constexpr int TSTEPS = 200;  // timesteps
constexpr int BLK = 512;     // 8 waves -> 2 waves/SIMD (proven optimum)

typedef _Float16 half8 __attribute__((ext_vector_type(8)));
typedef __fp16 h8v __attribute__((ext_vector_type(8)));
typedef float f32x4 __attribute__((ext_vector_type(4)));

__device__ __forceinline__ float4 ldg4(const float* p) {
  return *reinterpret_cast<const float4*>(p);
}
__device__ __forceinline__ float clamp01(float v) {
  return fminf(fmaxf(v, 0.0f), 1.0f);
}
// LDS-visibility barrier that does NOT drain vmcnt (stores stay in flight).
__device__ __forceinline__ void step_barrier() {
  asm volatile("s_waitcnt lgkmcnt(0)" ::: "memory");
  __builtin_amdgcn_s_barrier();
  asm volatile("" ::: "memory");
}
// pack two f32 -> f16x2 (RTZ)
__device__ __forceinline__ unsigned pkrtz(float a, float b) {
  typedef __fp16 h2v __attribute__((ext_vector_type(2)));
  h2v r = __builtin_amdgcn_cvt_pkrtz(a, b);
  return __builtin_bit_cast(unsigned, r);
}
// elementwise f16x8 multiply (4x v_pk_mul_f16)
__device__ __forceinline__ uint4 pkmul4(uint4 a, uint4 b) {
  h8v x = __builtin_bit_cast(h8v, a);
  h8v y = __builtin_bit_cast(h8v, b);
  h8v z = x * y;
  return __builtin_bit_cast(uint4, z);
}
// rotate-add within 16-lane DPP row: 0x121/0x122/0x124/0x128 = ror 1/2/4/8
template <int CTRL>
__device__ __forceinline__ float dpp_radd(float x) {
  int yi = __builtin_amdgcn_update_dpp(0, __float_as_int(x), CTRL, 0xF, 0xF, true);
  return x + __int_as_float(yi);
}
// fetch value from lane^1 (quad_perm [1,0,3,2])
__device__ __forceinline__ float dpp_xor1(float x) {
  int yi = __builtin_amdgcn_update_dpp(0, __float_as_int(x), 0xB1, 0xF, 0xF, true);
  return __int_as_float(yi);
}
// Swizzled uint4 (8 f16) index into f16 Q: 16 quads/row, XOR row-octet
__device__ __forceinline__ int qidx16(int row, int ch) {
  return (row << 4) + (ch ^ ((row >> 3) & 7));
}
__device__ __forceinline__ half8 h8(uint4 v) {
  return __builtin_bit_cast(half8, v);
}

__global__ __launch_bounds__(BLK, 2)
void sir_meta_kernel(const float* __restrict__ Rg,
                     const float* __restrict__ Tg,
                     const float* __restrict__ rho0g,
                     const float* __restrict__ betag,
                     float* __restrict__ outg)
{
  __shared__ __align__(16) float rs[MP];          // 1/rowsum (f32 exact)
  __shared__ __align__(16) unsigned binv16[64];   // beta/neff as f16 pairs
  __shared__ __align__(16) float scr[BLK];
  __shared__ __align__(16) unsigned xh[2][64];    // x as f16 pairs, dbuffered
  __shared__ __align__(16) uint4 q16[MP * 16];    // RAW R in f16 pairs (32KB)
  __shared__ __align__(16) uint4 gh[MP * 16];     // G in f16 pairs (8KB)

  const int tid = threadIdx.x;
  const int n = blockIdx.x;
  const float* __restrict__ Rn = Rg + (size_t)n * MP * MP;

  // ---- S1+S3a fused: stage RAW R as f16 (swizzled) AND row sums -> rs ----
  // Each iter: 32 rows, 16 lanes/row each holding 8 consecutive floats.
  {
    #pragma unroll
    for (int u = 0; u < 4; ++u) {
      const int fi8 = u * BLK + tid;
      const int r = fi8 >> 4, c8 = fi8 & 15;
      float4 lo = ldg4(Rn + r * MP + c8 * 8);
      float4 hi = ldg4(Rn + r * MP + c8 * 8 + 4);
      uint4 w;
      w.x = pkrtz(lo.x, lo.y);
      w.y = pkrtz(lo.z, lo.w);
      w.z = pkrtz(hi.x, hi.y);
      w.w = pkrtz(hi.z, hi.w);
      q16[qidx16(r, c8)] = w;
      // fused row sum: 16-lane DPP reduce of per-lane 8-float partials
      float p = ((lo.x + lo.y) + (lo.z + lo.w)) + ((hi.x + hi.y) + (hi.z + hi.w));
      p = dpp_radd<0x121>(p);
      p = dpp_radd<0x122>(p);
      p = dpp_radd<0x124>(p);
      p = dpp_radd<0x128>(p);
      if ((tid & 15) == 0) rs[r] = 1.0f / p;
    }
  }
  __syncthreads();

  // ---- S2: neff[c] = sum_i Rraw[i][c]*rs[i] (global coalesced, L2-hot) ----
  {
    const int c = tid & 127;
    const int h = tid >> 7;
    float a = 0.0f;
    #pragma unroll 8
    for (int i = 0; i < 32; ++i) {
      const int ig = h * 32 + i;
      a = fmaf(Rn[ig * MP + c], rs[ig], a);
    }
    scr[tid] = a;
  }
  __syncthreads();
  // binv16 pack directly from scr: lane t handles columns 2t, 2t+1
  if (tid < 64) {
    const float beta = betag[n];
    const int c0 = 2 * tid;
    const float s0 = ((scr[c0] + scr[c0 + 128]) + (scr[c0 + 256] + scr[c0 + 384]));
    const float s1 = ((scr[c0 + 1] + scr[c0 + 129]) + (scr[c0 + 257] + scr[c0 + 385]));
    binv16[tid] = pkrtz(beta / s0, beta / s1);
  }
  // initial x as f16 pairs (independent of binv; same barrier covers both)
  if (tid >= 64 && tid < 128) {
    const int t = tid - 64;
    const float* xp = rho0g + ((size_t)n * MP + 2 * t) * 3;
    xh[0][t] = pkrtz(xp[0], xp[3]);
  }
  __syncthreads();

  // ---- S3b: MFMA GEMM. Wave J computes G tiles (I=0..7, J). ----
  // A = raw R tile-I rows; B = binv-scaled tile-J (R17-verified).
  // D (m89): lane(col,kg) reg r = G[16I+4kg+r][16J+col] (pre-scale).
  {
    const int J = tid >> 6;
    const int l = tid & 63;
    const int col = l & 15;
    const int kg = l >> 4;
    const uint4* bnv4 = reinterpret_cast<const uint4*>(binv16);
    uint4 bfj[4];
    #pragma unroll
    for (int c = 0; c < 4; ++c)
      bfj[c] = pkmul4(q16[qidx16(16 * J + col, 4 * c + kg)], bnv4[4 * c + kg]);
    const float rscol = rs[16 * J + col];
    unsigned* ghu = reinterpret_cast<unsigned*>(gh);
    #pragma unroll
    for (int I = 0; I < 8; ++I) {
      const uint4 af0 = q16[qidx16(16 * I + col, 0 + kg)];
      const uint4 af1 = q16[qidx16(16 * I + col, 4 + kg)];
      const uint4 af2 = q16[qidx16(16 * I + col, 8 + kg)];
      const uint4 af3 = q16[qidx16(16 * I + col, 12 + kg)];
      f32x4 a = {0.f, 0.f, 0.f, 0.f};
      a = __builtin_amdgcn_mfma_f32_16x16x32_f16(h8(af0), h8(bfj[0]), a, 0, 0, 0);
      a = __builtin_amdgcn_mfma_f32_16x16x32_f16(h8(af1), h8(bfj[1]), a, 0, 0, 0);
      a = __builtin_amdgcn_mfma_f32_16x16x32_f16(h8(af2), h8(bfj[2]), a, 0, 0, 0);
      a = __builtin_amdgcn_mfma_f32_16x16x32_f16(h8(af3), h8(bfj[3]), a, 0, 0, 0);
      #pragma unroll
      for (int r = 0; r < 4; ++r) {
        const int ROW = 16 * I + 4 * kg + r;
        const float val = a[r] * rs[ROW] * rscol;
        const float nb = dpp_xor1(val);            // neighbor col's scaled val
        if ((col & 1) == 0)
          ghu[ROW * 64 + 8 * J + (col >> 1)] = pkrtz(val, nb);
      }
    }
  }
  __syncthreads();

  // ---- R14 loop (verbatim): wave w owns G rows [16w..16w+16) ----
  const int w = tid >> 6;
  const int l = tid & 63;
  const int col = l & 15;
  const int kg = l >> 4;
  const int jrow = 16 * w + 4 * kg + col;   // this lane's state row (col<4)
  const bool writer = (col < 4);

  uint4 af0 = gh[(16 * w + col) * 16 + 0 + kg];
  uint4 af1 = gh[(16 * w + col) * 16 + 4 + kg];
  uint4 af2 = gh[(16 * w + col) * 16 + 8 + kg];
  uint4 af3 = gh[(16 * w + col) * 16 + 12 + kg];

  const float* Tn = Tg + n * 9;
  const float T00 = Tn[0], T01 = Tn[1], T02 = Tn[2];
  const float T10 = Tn[3], T11 = Tn[4], T12 = Tn[5];
  const float T20 = Tn[6], T21 = Tn[7], T22 = Tn[8];

  float r0 = 0.f, r1 = 0.f, r2 = 0.f;
  if (writer) {
    const float* rp = rho0g + ((size_t)n * MP + jrow) * 3;
    r0 = rp[0]; r1 = rp[1]; r2 = rp[2];
  }

  float4* outp = reinterpret_cast<float4*>(outg) + (size_t)n * TSTEPS * MP + jrow;
  const bool xwriter = writer && ((col & 1) == 0);
  const int xslot = jrow >> 1;              // valid when col even

  for (int s = 0; s < TSTEPS; ++s) {
    // chain head: 4 broadcast uint4 x-reads (4 distinct addrs/wave)
    const uint4* xq4 = reinterpret_cast<const uint4*>(&xh[s & 1][0]);
    const uint4 b0 = xq4[kg];
    const uint4 b1 = xq4[4 + kg];
    const uint4 b2 = xq4[8 + kg];
    const uint4 b3 = xq4[12 + kg];

    // off-chain: emit pre-update state (coalesced 16-lane store per wave)
    const float S = 1.0f - ((r0 + r1) + r2);
    if (writer) *outp = make_float4(S, r0, r1, r2);
    outp += MP;

    // two 2-deep MFMA chains (K = 128 in 32-chunks), summed at select
    f32x4 accA = {0.f, 0.f, 0.f, 0.f};
    f32x4 accB = {0.f, 0.f, 0.f, 0.f};
    accA = __builtin_amdgcn_mfma_f32_16x16x32_f16(h8(af0), h8(b0), accA, 0, 0, 0);
    accB = __builtin_amdgcn_mfma_f32_16x16x32_f16(h8(af1), h8(b1), accB, 0, 0, 0);
    accA = __builtin_amdgcn_mfma_f32_16x16x32_f16(h8(af2), h8(b2), accA, 0, 0, 0);
    accB = __builtin_amdgcn_mfma_f32_16x16x32_f16(h8(af3), h8(b3), accB, 0, 0, 0);

    // static select of this lane's row-sum (reg index = col, cndmask tree)
    const float tA0 = (col & 1) ? accA[1] : accA[0];
    const float tA1 = (col & 1) ? accA[3] : accA[2];
    const float tB0 = (col & 1) ? accB[1] : accB[0];
    const float tB1 = (col & 1) ? accB[3] : accB[2];
    const float y = ((col & 2) ? tA1 : tA0) + ((col & 2) ? tB1 : tB0);

    // state update + clip
    const float ni = S * y;
    const float n0 = clamp01(fmaf(r0, T00, fmaf(r1, T10, fmaf(r2, T20, ni))));
    const float n1 = clamp01(fmaf(r0, T01, fmaf(r1, T11, r2 * T21)));
    const float n2 = clamp01(fmaf(r0, T02, fmaf(r1, T12, r2 * T22)));

    // pack adjacent rows' n0 (col pairs 0-1, 2-3 via quad_perm xor1)
    const float nb = dpp_xor1(n0);
    if (xwriter) xh[(s & 1) ^ 1][xslot] = pkrtz(n0, nb);

    r0 = n0; r1 = n1; r2 = n2;

    // LDS-only barrier: x write visible; global stores stay in flight
    step_barrier();
  }
}

} // namespace

extern "C" void kernel_launch(void* const* d_in, const int* in_sizes, int n_in,
                              void* d_out, int out_size, void* d_ws, size_t ws_size,
                              hipStream_t stream)
{
  const float* Rg    = (const float*)d_in[0];
  const float* Tg    = (const float*)d_in[1];
  const float* rho0g = (const float*)d_in[2];
  const float* betag = (const float*)d_in[3];
  float* outg = (float*)d_out;
  sir_meta_kernel<<<NS, BLK, 0, stream>>>(Rg, Tg, rho0g, betag, outg);
}